// Round 4
// baseline (690.488 us; speedup 1.0000x reference)
//
#include <hip/hip_runtime.h>
#include <hip/hip_fp16.h>

// ---------------------------------------------------------------------------
// VQFFN1: out = softmax(rmsnorm(x) @ rmsnorm(w)^T) @ w
//   x: [16384,1024] fp32   w: [4096,1024] fp32   out: [16384,1024] fp32
// fp32 scores; GEMM2 plain fp16 + split-K + f32 HW atomics.
// R2: XOR-swizzled LDS (bank conflicts 3.8e7 -> 0).
// R5: S = (xh + xl) @ wh^T; shared WH tile + b-frags across both passes.
// R7 FAILED: gemm2 split-K 4 (occupancy not the lever; drain structural).
// R8: gemm2 BK 64->128: 650us; gemm1 dominant at MfmaUtil 43%.
// R9 NEUTRAL: 4-phase pipeline, wave tile 64x64: reads/phase (768cyc/CU) >
//     MFMA/phase (659cyc/CU) -> phase period read-bound, util 40%. Lesson:
//     phase discipline only pays with m201's read:MFMA economics.
// R10: gemm1 = faithful m201 geometry. BM=BN=256, BK=64, 512thr, wave tile
//     128x64, 8 phases/K-tile (4 hi + 4 lo quadrants, 16 MFMA each), b-frags
//     reg-cached across hi+lo (B read once/K-tile; 40 reads vs 128 MFMA).
//     LDS 128KB: B dbuf + Ah single + Al single; staging 2 rounds/phase;
//     waits vmcnt(4)@PH4 (drain Al, B flying) and vmcnt(0)@PH8 (youngest
//     load 2 phases old). Grid 16x16 = 256 = 1 block/CU exactly.
// ---------------------------------------------------------------------------

#define D_MODEL 1024
#define D_FF    4096
#define M_ROWS  16384
#define MC      4096

typedef _Float16 half8 __attribute__((ext_vector_type(8)));
typedef _Float16 half4 __attribute__((ext_vector_type(4)));
typedef float    floatx4 __attribute__((ext_vector_type(4)));

// async global->LDS, 16B/lane; LDS dst = wave-uniform base + lane*16 (m97)
__device__ __forceinline__ void gld_lds16(const void* g, void* l) {
  __builtin_amdgcn_global_load_lds(
      (const __attribute__((address_space(1))) void*)g,
      (__attribute__((address_space(3))) void*)l, 16, 0, 0);
}

// ---------------------------------------------------------------------------
// rmsnorm (fp32 in) + hi/lo fp16 split. One wave per row of 1024.
// ---------------------------------------------------------------------------
#define MB_X (M_ROWS / 4)
#define MB_W (D_FF / 4)
__global__ __launch_bounds__(256) void rmsnorm_split_kernel(
    const float* __restrict__ X, _Float16* __restrict__ XH,
    _Float16* __restrict__ XL, const float* __restrict__ W,
    _Float16* __restrict__ WH, _Float16* __restrict__ WL) {
  const int lane = threadIdx.x & 63;
  const bool isW = blockIdx.x >= MB_X;
  const long row = (long)(isW ? blockIdx.x - MB_X : blockIdx.x) * 4 +
                   (threadIdx.x >> 6);
  const float* x = (isW ? W : X) + row * D_MODEL;
  _Float16* YH = (isW ? WH : XH) + row * D_MODEL;
  _Float16* YL = (isW ? WL : XL) + row * D_MODEL;

  float v[16];
  float ss = 0.f;
#pragma unroll
  for (int s = 0; s < 4; s++) {
    const float4 f = *(const float4*)(x + s * 256 + lane * 4);
    v[s * 4 + 0] = f.x; v[s * 4 + 1] = f.y;
    v[s * 4 + 2] = f.z; v[s * 4 + 3] = f.w;
    ss += f.x * f.x + f.y * f.y + f.z * f.z + f.w * f.w;
  }
#pragma unroll
  for (int off = 32; off >= 1; off >>= 1) ss += __shfl_xor(ss, off);
  const float inv = rsqrtf(ss * (1.0f / D_MODEL) + 1e-6f);
#pragma unroll
  for (int s = 0; s < 4; s++) {
    half4 h, l;
#pragma unroll
    for (int j = 0; j < 4; j++) {
      const float t = v[s * 4 + j] * inv;
      const _Float16 hi = (_Float16)t;
      h[j] = hi;
      l[j] = (_Float16)(t - (float)hi);
    }
    *(half4*)(YH + s * 256 + lane * 4) = h;
    *(half4*)(YL + s * 256 + lane * 4) = l;
  }
}

// ---------------------------------------------------------------------------
// transpose w [4096,1024] fp32 -> wT [1024,4096] fp16 (unnormalized, GEMM2 B)
// ---------------------------------------------------------------------------
__global__ __launch_bounds__(256) void transpose_kernel(
    const float* __restrict__ W, _Float16* __restrict__ WT) {
  __shared__ _Float16 tile[32][33];
  const int tx = threadIdx.x & 31;
  const int ty = threadIdx.x >> 5;  // 0..7
  const int d0 = blockIdx.x * 32;
  const int c0 = blockIdx.y * 32;
#pragma unroll
  for (int i = 0; i < 32; i += 8)
    tile[ty + i][tx] = (_Float16)W[(long)(c0 + ty + i) * D_MODEL + d0 + tx];
  __syncthreads();
#pragma unroll
  for (int i = 0; i < 32; i += 8)
    WT[(long)(d0 + ty + i) * D_FF + c0 + tx] = tile[tx][ty + i];
}

// ---------------------------------------------------------------------------
// GEMM1: S[4096,4096] fp32 = (xh + xl) @ wh^T over K=1024.  (R10 structure)
// LDS tiles [row][64] f16 with R2 XOR swizzle: slot s holds global k-slot
// s ^ (row&7); staging pre-swizzles the global source column; fragment reads
// XOR the k-slot with m16&7 -> conflict-free ds_read_b128 (verified 0).
// ---------------------------------------------------------------------------
__global__ __launch_bounds__(512, 2) void gemm1_kernel(
    const _Float16* __restrict__ XH, const _Float16* __restrict__ XL,
    const _Float16* __restrict__ WH, float* __restrict__ S) {
  __shared__ _Float16 Bs2[2][256 * 64];  // 64 KB (dbuf)
  __shared__ _Float16 AhT[256 * 64];     // 32 KB (single)
  __shared__ _Float16 AlT[256 * 64];     // 32 KB (single)
  const int tid = threadIdx.x;
  const int lane = tid & 63, wave = tid >> 6;

  // XCD-chunked bijective swizzle (256 blocks; chunk = 2 row-panels/XCD)
  const int bid = blockIdx.y * 16 + blockIdx.x;
  const int lg = ((bid & 7) << 5) | (bid >> 3);
  const int by = lg >> 4, bx = lg & 15;
  const long rowBase = (long)by * 256;
  const long colBase = (long)bx * 256;

  // staging: thread t covers (row = r*64 + (t>>3), slot = t&7) of a tile
  const int srow = tid >> 3;                       // 0..63
  const int scol = ((tid & 7) ^ (srow & 7)) * 8;   // pre-swizzled source col
  const _Float16* Bg  = WH + (colBase + srow) * (long)D_MODEL + scol;
  const _Float16* Ahg = XH + (rowBase + srow) * (long)D_MODEL + scol;
  const _Float16* Alg = XL + (rowBase + srow) * (long)D_MODEL + scol;
  const int dstOff = tid * 8;  // f16 units; round r adds r*4096

  const int wr = wave >> 2, wc = wave & 3;  // wave tile: rows 128, cols 64
  const int m16 = lane & 15, q = lane >> 4, mx7 = m16 & 7;
  const int aBase = wr * 128, bBase = wc * 64;

  floatx4 acc[8][4] = {};
  half8 a[2][4], b[2][4];

#define LD_A(T, QR)                                                            \
  _Pragma("unroll") for (int ks = 0; ks < 2; ks++)                             \
  _Pragma("unroll") for (int mf = 0; mf < 4; mf++)                             \
      a[ks][mf] = *(const half8*)(&T[(aBase + (QR)*64 + mf * 16 + m16) * 64 +  \
                                     (((ks * 4 + q) ^ mx7)) * 8]);
#define LD_B(CUR, QC)                                                          \
  _Pragma("unroll") for (int ks = 0; ks < 2; ks++)                             \
  _Pragma("unroll") for (int nf = 0; nf < 2; nf++)                             \
      b[ks][(QC)*2 + nf] =                                                     \
          *(const half8*)(&Bs2[CUR][(bBase + (QC)*32 + nf * 16 + m16) * 64 +   \
                                    (((ks * 4 + q) ^ mx7)) * 8]);
#define MM(QR, QC)                                                             \
  __builtin_amdgcn_s_setprio(1);                                               \
  _Pragma("unroll") for (int ks = 0; ks < 2; ks++)                             \
  _Pragma("unroll") for (int mf = 0; mf < 4; mf++)                             \
  _Pragma("unroll") for (int nf = 0; nf < 2; nf++)                             \
      acc[(QR)*4 + mf][(QC)*2 + nf] = __builtin_amdgcn_mfma_f32_16x16x32_f16(  \
          a[ks][mf], b[ks][(QC)*2 + nf], acc[(QR)*4 + mf][(QC)*2 + nf],        \
          0, 0, 0);                                                            \
  __builtin_amdgcn_s_setprio(0);
#define STG(G, T, R, KT) \
  gld_lds16((G) + (long)(R)*64 * D_MODEL + (KT), &(T)[(R)*4096 + dstOff]);
#define BAR() __builtin_amdgcn_s_barrier()

  // ---- prologue: B(0)->buf0, Ah(0) ----
  {
#pragma unroll
    for (int r = 0; r < 4; r++) STG(Bg, Bs2[0], r, 0);
#pragma unroll
    for (int r = 0; r < 4; r++) STG(Ahg, AhT, r, 0);
    asm volatile("s_waitcnt vmcnt(0)" ::: "memory");
    BAR();
    __builtin_amdgcn_sched_barrier(0);
  }

#pragma unroll 2
  for (int i = 0; i < 16; i++) {
    const int cur = i & 1, nxt = cur ^ 1;
    const long kt0 = (long)i * 64, kt1 = kt0 + 64;
    const bool last = (i == 15);

    // PH1 (hi qr0 qc0): a_hi[qr0] + b[qc0]; stage Al(i) r0,r1
    LD_A(AhT, 0);
    LD_B(cur, 0);
    STG(Alg, AlT, 0, kt0);
    STG(Alg, AlT, 1, kt0);
    BAR(); MM(0, 0); BAR();

    // PH2 (hi qr0 qc1): b[qc1]; stage Al(i) r2,r3
    LD_B(cur, 1);
    STG(Alg, AlT, 2, kt0);
    STG(Alg, AlT, 3, kt0);
    BAR(); MM(0, 1); BAR();

    // PH3 (hi qr1 qc0): a_hi[qr1]; stage B[nxt] r0,r1
    LD_A(AhT, 1);
    if (!last) { STG(Bg, Bs2[nxt], 0, kt1); STG(Bg, Bs2[nxt], 1, kt1); }
    BAR(); MM(1, 0); BAR();

    // PH4 (hi qr1 qc1): stage B[nxt] r2,r3; drain Al(i) (B stays in flight)
    if (!last) {
      STG(Bg, Bs2[nxt], 2, kt1);
      STG(Bg, Bs2[nxt], 3, kt1);
      asm volatile("s_waitcnt vmcnt(4)" ::: "memory");
    } else {
      asm volatile("s_waitcnt vmcnt(0)" ::: "memory");
    }
    BAR(); MM(1, 1); BAR();
    __builtin_amdgcn_sched_barrier(0);  // PH5 Al-reads stay below

    // PH5 (lo qr0 qc0): a_lo[qr0]; stage Ah(i+1) r0,r1
    LD_A(AlT, 0);
    if (!last) { STG(Ahg, AhT, 0, kt1); STG(Ahg, AhT, 1, kt1); }
    BAR(); MM(0, 0); BAR();

    // PH6 (lo qr0 qc1): stage Ah(i+1) r2,r3
    if (!last) { STG(Ahg, AhT, 2, kt1); STG(Ahg, AhT, 3, kt1); }
    BAR(); MM(0, 1); BAR();

    // PH7 (lo qr1 qc0): a_lo[qr1]
    LD_A(AlT, 1);
    BAR(); MM(1, 0); BAR();

    // PH8 (lo qr1 qc1): drain B[nxt]+Ah(i+1) (youngest ~2 phases old)
    if (!last) asm volatile("s_waitcnt vmcnt(0)" ::: "memory");
    BAR(); MM(1, 1); BAR();
    __builtin_amdgcn_sched_barrier(0);  // next PH1 reads stay below
  }
#undef LD_A
#undef LD_B
#undef MM
#undef STG
#undef BAR

  // C/D frag: col = lane&15, row = quad*4 + reg  [m89/m91 verified]
#pragma unroll
  for (int ai = 0; ai < 8; ai++)
#pragma unroll
    for (int r = 0; r < 4; r++) {
      const long rr =
          rowBase + wr * 128 + (ai >> 2) * 64 + (ai & 3) * 16 + q * 4 + r;
#pragma unroll
      for (int bi = 0; bi < 4; bi++)
        S[rr * D_FF + colBase + wc * 64 + (bi >> 1) * 32 + (bi & 1) * 16 +
          m16] = acc[ai][bi][r];
    }
}

// GEMM2: O[4096,1024] fp32 += P[4096, lda 8192] @ WT[1024,4096]^T
// 128x128 tile, BK=128 (R8), split-K=2, HW f32 atomics into pre-zeroed O.
__global__ __launch_bounds__(256, 2) void gemm2_kernel(
    const _Float16* __restrict__ P, const _Float16* __restrict__ WT,
    float* __restrict__ O) {
  constexpr int BK = 128, K = D_FF, LDA = 2 * D_FF, KSPLIT = 2048;
  __shared__ _Float16 As[128 * BK];  // 32 KB
  __shared__ _Float16 Bs[128 * BK];  // 32 KB
  const int tid = threadIdx.x;
  const int wave = tid >> 6, lane = tid & 63;

  // XCD-chunked bijective swizzle (nwg = 8*32*2 = 512, %8 == 0)
  const int bid = ((blockIdx.z * 32 + blockIdx.y) << 3) | blockIdx.x;
  const int swz = ((bid & 7) << 6) | (bid >> 3);
  const int bx = swz & 7;          // col-block   0..7
  const int by = (swz >> 3) & 31;  // row-block   0..31
  const int bz = swz >> 8;         // K-split     0..1

  const long rowBase = (long)by * 128;
  const long colBase = (long)bx * 128;
  const int k0 = bz * KSPLIT;

  // staging geometry: 1 gld_lds16 instr = 1KB = 4 rows x 256B
  const int srow4 = lane >> 4;              // 0..3
  const int slotE = (lane & 15) ^ srow4;    // even-i swizzled 16B slot
  const int slotO = slotE ^ 4;              // odd-i  (row&7 gains +4)
  const _Float16* AgE = P + (rowBase + wave * 32 + srow4) * (long)LDA + slotE * 8;
  const _Float16* AgO = P + (rowBase + wave * 32 + srow4) * (long)LDA + slotO * 8;
  const _Float16* BgE = WT + (colBase + wave * 32 + srow4) * (long)K + slotE * 8;
  const _Float16* BgO = WT + (colBase + wave * 32 + srow4) * (long)K + slotO * 8;
  _Float16* AsW = As + wave * 4096 + lane * 8;  // 32 rows/wave * 128
  _Float16* BsW = Bs + wave * 4096 + lane * 8;
  const int wr = wave >> 1, wc = wave & 1;
  const int m16 = lane & 15, q = lane >> 4;
  const int mx7 = m16 & 7;

  floatx4 acc[4][4] = {};

  for (int kt = k0; kt < k0 + KSPLIT; kt += BK) {
#pragma unroll
    for (int i = 0; i < 8; i++) {
      const _Float16* ag = (i & 1) ? AgO : AgE;
      const _Float16* bg = (i & 1) ? BgO : BgE;
      gld_lds16(ag + (long)i * 4 * LDA + kt, AsW + i * 512);
      gld_lds16(bg + (long)i * 4 * K + kt, BsW + i * 512);
    }
    __syncthreads();
#pragma unroll
    for (int ks = 0; ks < 4; ks++) {
      const int kx = ((ks * 4 + q) ^ mx7) * 8;
      half8 a[4], b[4];
#pragma unroll
      for (int mi = 0; mi < 4; mi++)
        a[mi] = *(const half8*)(&As[(wr * 64 + mi * 16 + m16) * BK + kx]);
#pragma unroll
      for (int ni = 0; ni < 4; ni++)
        b[ni] = *(const half8*)(&Bs[(wc * 64 + ni * 16 + m16) * BK + kx]);
#pragma unroll
      for (int mi = 0; mi < 4; mi++)
#pragma unroll
        for (int ni = 0; ni < 4; ni++)
          acc[mi][ni] = __builtin_amdgcn_mfma_f32_16x16x32_f16(
              a[mi], b[ni], acc[mi][ni], 0, 0, 0);
    }
    __syncthreads();
  }

#pragma unroll
  for (int mi = 0; mi < 4; mi++)
#pragma unroll
    for (int r = 0; r < 4; r++) {
      const long rr = rowBase + wr * 64 + mi * 16 + q * 4 + r;
#pragma unroll
      for (int ni = 0; ni < 4; ni++)
        unsafeAtomicAdd(&O[rr * D_MODEL + colBase + wc * 64 + ni * 16 + m16],
                        acc[mi][ni][r]);
    }
}

// ---------------------------------------------------------------------------
// softmax over rows of 4096: fp32 S in, fp16 P out in-place at row start.
// ---------------------------------------------------------------------------
__global__ __launch_bounds__(256) void softmax_kernel(float* __restrict__ S) {
  float* s = S + (long)blockIdx.x * D_FF;
  const int t = threadIdx.x;
  const int lane = t & 63, wave = t >> 6;
  __shared__ float redm[4], redl[4];

  float v[16];
  float mx = -3.4e38f;
#pragma unroll
  for (int seg = 0; seg < 4; seg++) {
    const float4 f = *(const float4*)(s + seg * 1024 + t * 4);
    v[seg * 4 + 0] = f.x; v[seg * 4 + 1] = f.y;
    v[seg * 4 + 2] = f.z; v[seg * 4 + 3] = f.w;
  }
#pragma unroll
  for (int j = 0; j < 16; j++) mx = fmaxf(mx, v[j]);
#pragma unroll
  for (int off = 32; off >= 1; off >>= 1) mx = fmaxf(mx, __shfl_xor(mx, off));
  if (lane == 0) redm[wave] = mx;
  __syncthreads();
  const float m = fmaxf(fmaxf(redm[0], redm[1]), fmaxf(redm[2], redm[3]));

  float sum = 0.f;
#pragma unroll
  for (int j = 0; j < 16; j++) {
    v[j] = __expf(v[j] - m);
    sum += v[j];
  }
#pragma unroll
  for (int off = 32; off >= 1; off >>= 1) sum += __shfl_xor(sum, off);
  if (lane == 0) redl[wave] = sum;
  __syncthreads();
  const float inv = 1.f / (redl[0] + redl[1] + redl[2] + redl[3]);

  _Float16* p = (_Float16*)s;  // all reads of this row completed above
#pragma unroll
  for (int seg = 0; seg < 4; seg++) {
    half4 h;
#pragma unroll
    for (int j = 0; j < 4; j++) h[j] = (_Float16)(v[seg * 4 + j] * inv);
    *(half4*)(p + seg * 1024 + t * 4) = h;
  }
}

// ---------------------------------------------------------------------------
extern "C" void kernel_launch(void* const* d_in, const int* in_sizes, int n_in,
                              void* d_out, int out_size, void* d_ws, size_t ws_size,
                              hipStream_t stream) {
  const float* x = (const float*)d_in[0];  // [16384,1024] fp32
  const float* w = (const float*)d_in[1];  // [4096,1024] fp32
  float* out = (float*)d_out;              // [16384,1024] fp32

  // ws layout: xh 32Mi | xl 32Mi | wh 8Mi | wl 8Mi | wT 8Mi | S 64Mi = 152Mi
  const size_t NEED = 152ull << 20;
  if (ws_size < NEED) return;

  char* ws = (char*)d_ws;
  _Float16* xh = (_Float16*)(ws);
  _Float16* xl = (_Float16*)(ws + (32ull << 20));
  _Float16* wh = (_Float16*)(ws + (64ull << 20));
  _Float16* wl = (_Float16*)(ws + (72ull << 20));  // written, unused (R5)
  _Float16* wT = (_Float16*)(ws + (80ull << 20));
  float*    S  = (float*)   (ws + (88ull << 20));

  // gemm2 accumulates via atomics -> zero d_out first (graph-capture safe)
  hipMemsetAsync(d_out, 0, (size_t)M_ROWS * D_MODEL * sizeof(float), stream);

  hipLaunchKernelGGL(rmsnorm_split_kernel, dim3(MB_X + MB_W), dim3(256), 0,
                     stream, x, xh, xl, w, wh, wl);
  hipLaunchKernelGGL(transpose_kernel, dim3(D_MODEL / 32, D_FF / 32), dim3(256),
                     0, stream, w, wT);

  for (int c = 0; c < M_ROWS / MC; c++) {
    const long ro = (long)c * MC;
    hipLaunchKernelGGL(gemm1_kernel, dim3(16, 16), dim3(512), 0,
                       stream, xh + ro * D_MODEL, xl + ro * D_MODEL, wh, S);
    hipLaunchKernelGGL(softmax_kernel, dim3(MC), dim3(256), 0, stream, S);
    hipLaunchKernelGGL(gemm2_kernel, dim3(D_MODEL / 128, MC / 128, 2),
                       dim3(256), 0, stream, (const _Float16*)S, wT,
                       out + ro * D_MODEL);
  }
}